// Round 2
// baseline (1360.711 us; speedup 1.0000x reference)
//
#include <hip/hip_runtime.h>
#include <hip/hip_bf16.h>
#include <cstddef>
#include <cstdint>

#define N_NODES 100000
#define N_EDGES 800000
#define HID 64
#define EPS 1e-5f

// Broadcast lane k's value of v to all lanes (wave-uniform data path).
__device__ __forceinline__ float bcast(float v, int k) {
  return __builtin_bit_cast(float, __builtin_amdgcn_readlane(__builtin_bit_cast(int, v), k));
}

// ---------------------------------------------------------------------------
// Edge MLP, layer 1: h1[e] = concat(x[row[e]], ea[e]) @ W1a + b1a
// Also accumulates per-column sum / sumsq for BatchNorm batch stats.
// Wave-per-edge; lane j owns output column j. W (128x64) staged in LDS.
// ---------------------------------------------------------------------------
__global__ __launch_bounds__(256, 4)
void edge_mlp1(const float* __restrict__ x, const int* __restrict__ ei_row,
               const float* __restrict__ ea, const float* __restrict__ W1,
               const float* __restrict__ b1,
               __hip_bfloat16* __restrict__ h1, float* __restrict__ stats) {
  __shared__ float Wlds[128 * 64];
  __shared__ float bias[64];
  __shared__ float red[4][128];

  int tid = threadIdx.x;
  // Stage W1a: 8192 floats, 256 threads x 8 float4
  const float4* W4 = (const float4*)W1;
  float4* Wl4 = (float4*)Wlds;
#pragma unroll
  for (int i = 0; i < 8; i++) Wl4[tid + 256 * i] = W4[tid + 256 * i];
  if (tid < 64) bias[tid] = b1[tid];
  __syncthreads();

  int lane = tid & 63;
  int w = __builtin_amdgcn_readfirstlane(tid >> 6);
  int wave = blockIdx.x * 4 + w;
  int nw = gridDim.x * 4;

  float psum = 0.f, psq = 0.f;
  for (int e = wave; e < N_EDGES; e += nw) {
    int row = ei_row[e];
    float vx = x[(size_t)row * 64 + lane];
    float ve = ea[(size_t)e * 64 + lane];
    float acc = bias[lane];
#pragma unroll
    for (int k = 0; k < 64; k++)
      acc = fmaf(bcast(vx, k), Wlds[k * 64 + lane], acc);
#pragma unroll
    for (int k = 0; k < 64; k++)
      acc = fmaf(bcast(ve, k), Wlds[(64 + k) * 64 + lane], acc);
    h1[(size_t)e * 64 + lane] = __float2bfloat16(acc);
    psum += acc;
    psq += acc * acc;
  }
  red[w][lane] = psum;
  red[w][64 + lane] = psq;
  __syncthreads();
  if (tid < 64) {
    float s = red[0][tid] + red[1][tid] + red[2][tid] + red[3][tid];
    float q = red[0][64 + tid] + red[1][64 + tid] + red[2][64 + tid] + red[3][64 + tid];
    atomicAdd(&stats[tid], s);
    atomicAdd(&stats[64 + tid], q);
  }
}

// ---------------------------------------------------------------------------
// BN finalize: stats (sum, sumsq) -> per-column scale/shift
// scale = g * rsqrt(var+eps); shift = be - mu*scale
// ---------------------------------------------------------------------------
__global__ void bn_finalize(const float* __restrict__ stats_in,
                            const float* __restrict__ g, const float* __restrict__ be,
                            float* __restrict__ scsh, float inv_count) {
  int j = threadIdx.x;
  float mu = stats_in[j] * inv_count;
  float var = stats_in[64 + j] * inv_count - mu * mu;
  float sc = g[j] * rsqrtf(var + EPS);
  scsh[j] = sc;
  scsh[64 + j] = be[j] - mu * sc;
}

// ---------------------------------------------------------------------------
// Edge MLP, layer 2: out_e = relu(bn(h1)) @ W2a + b2a, scatter-add by col.
// ---------------------------------------------------------------------------
__global__ __launch_bounds__(256, 4)
void edge_mlp2(const __hip_bfloat16* __restrict__ h1, const int* __restrict__ ei_col,
               const float* __restrict__ W2, const float* __restrict__ b2,
               const float* __restrict__ scsh,
               float* __restrict__ nodesum, float* __restrict__ cnt) {
  __shared__ float Wlds[64 * 64];
  __shared__ float bias[64], sc[64], sh[64];
  int tid = threadIdx.x;
  const float4* W4 = (const float4*)W2;
  float4* Wl4 = (float4*)Wlds;
#pragma unroll
  for (int i = 0; i < 4; i++) Wl4[tid + 256 * i] = W4[tid + 256 * i];
  if (tid < 64) {
    bias[tid] = b2[tid];
    sc[tid] = scsh[tid];
    sh[tid] = scsh[64 + tid];
  }
  __syncthreads();

  int lane = tid & 63;
  int w = __builtin_amdgcn_readfirstlane(tid >> 6);
  int wave = blockIdx.x * 4 + w;
  int nw = gridDim.x * 4;

  for (int e = wave; e < N_EDGES; e += nw) {
    float v = __bfloat162float(h1[(size_t)e * 64 + lane]);
    v = fmaf(v, sc[lane], sh[lane]);
    v = fmaxf(v, 0.f);
    float acc = bias[lane];
#pragma unroll
    for (int k = 0; k < 64; k++)
      acc = fmaf(bcast(v, k), Wlds[k * 64 + lane], acc);
    int col = ei_col[e];
    atomicAdd(&nodesum[(size_t)col * 64 + lane], acc);
    if (lane == 0) atomicAdd(&cnt[col], 1.f);
  }
}

// ---------------------------------------------------------------------------
// Node MLP, layer 1: h2[n] = concat(x[n], nodesum[n]/max(cnt,1)) @ W1b + b1b
// ---------------------------------------------------------------------------
__global__ __launch_bounds__(256, 4)
void node_mlp1(const float* __restrict__ x, const float* __restrict__ nodesum,
               const float* __restrict__ cnt, const float* __restrict__ W1,
               const float* __restrict__ b1,
               __hip_bfloat16* __restrict__ h2, float* __restrict__ stats) {
  __shared__ float Wlds[128 * 64];
  __shared__ float bias[64];
  __shared__ float red[4][128];
  int tid = threadIdx.x;
  const float4* W4 = (const float4*)W1;
  float4* Wl4 = (float4*)Wlds;
#pragma unroll
  for (int i = 0; i < 8; i++) Wl4[tid + 256 * i] = W4[tid + 256 * i];
  if (tid < 64) bias[tid] = b1[tid];
  __syncthreads();

  int lane = tid & 63;
  int w = __builtin_amdgcn_readfirstlane(tid >> 6);
  int wave = blockIdx.x * 4 + w;
  int nw = gridDim.x * 4;

  float psum = 0.f, psq = 0.f;
  for (int n = wave; n < N_NODES; n += nw) {
    float c = cnt[n];
    float inv = 1.0f / fmaxf(c, 1.f);
    float vx = x[(size_t)n * 64 + lane];
    float vm = nodesum[(size_t)n * 64 + lane] * inv;
    float acc = bias[lane];
#pragma unroll
    for (int k = 0; k < 64; k++)
      acc = fmaf(bcast(vx, k), Wlds[k * 64 + lane], acc);
#pragma unroll
    for (int k = 0; k < 64; k++)
      acc = fmaf(bcast(vm, k), Wlds[(64 + k) * 64 + lane], acc);
    h2[(size_t)n * 64 + lane] = __float2bfloat16(acc);
    psum += acc;
    psq += acc * acc;
  }
  red[w][lane] = psum;
  red[w][64 + lane] = psq;
  __syncthreads();
  if (tid < 64) {
    float s = red[0][tid] + red[1][tid] + red[2][tid] + red[3][tid];
    float q = red[0][64 + tid] + red[1][64 + tid] + red[2][64 + tid] + red[3][64 + tid];
    atomicAdd(&stats[tid], s);
    atomicAdd(&stats[64 + tid], q);
  }
}

// ---------------------------------------------------------------------------
// Node MLP, layer 2: out = relu(bn(h2)) @ W2b + b2b
// ---------------------------------------------------------------------------
__global__ __launch_bounds__(256, 4)
void node_mlp2(const __hip_bfloat16* __restrict__ h2, const float* __restrict__ W2,
               const float* __restrict__ b2, const float* __restrict__ scsh,
               float* __restrict__ out) {
  __shared__ float Wlds[64 * 64];
  __shared__ float bias[64], sc[64], sh[64];
  int tid = threadIdx.x;
  const float4* W4 = (const float4*)W2;
  float4* Wl4 = (float4*)Wlds;
#pragma unroll
  for (int i = 0; i < 4; i++) Wl4[tid + 256 * i] = W4[tid + 256 * i];
  if (tid < 64) {
    bias[tid] = b2[tid];
    sc[tid] = scsh[tid];
    sh[tid] = scsh[64 + tid];
  }
  __syncthreads();

  int lane = tid & 63;
  int w = __builtin_amdgcn_readfirstlane(tid >> 6);
  int wave = blockIdx.x * 4 + w;
  int nw = gridDim.x * 4;

  for (int n = wave; n < N_NODES; n += nw) {
    float v = __bfloat162float(h2[(size_t)n * 64 + lane]);
    v = fmaf(v, sc[lane], sh[lane]);
    v = fmaxf(v, 0.f);
    float acc = bias[lane];
#pragma unroll
    for (int k = 0; k < 64; k++)
      acc = fmaf(bcast(v, k), Wlds[k * 64 + lane], acc);
    out[(size_t)n * 64 + lane] = acc;
  }
}

// ---------------------------------------------------------------------------
extern "C" void kernel_launch(void* const* d_in, const int* in_sizes, int n_in,
                              void* d_out, int out_size, void* d_ws, size_t ws_size,
                              hipStream_t stream) {
  const float* x   = (const float*)d_in[0];
  const int*   ei  = (const int*)d_in[1];   // [2,E]: rows then cols
  const float* ea  = (const float*)d_in[2];
  // d_in[3] = u (unused), d_in[4] = batch (unused)
  const float* W1a = (const float*)d_in[5];
  const float* b1a = (const float*)d_in[6];
  const float* g1  = (const float*)d_in[7];
  const float* be1 = (const float*)d_in[8];
  const float* W2a = (const float*)d_in[9];
  const float* b2a = (const float*)d_in[10];
  const float* W1b = (const float*)d_in[11];
  const float* b1b = (const float*)d_in[12];
  const float* g2  = (const float*)d_in[13];
  const float* be2 = (const float*)d_in[14];
  const float* W2b = (const float*)d_in[15];
  const float* b2b = (const float*)d_in[16];
  float* out = (float*)d_out;

  // Workspace layout
  char* ws = (char*)d_ws;
  __hip_bfloat16* h1 = (__hip_bfloat16*)ws;                       // E*64 bf16 = 102.4 MB
  char* p = ws + (size_t)N_EDGES * 64 * sizeof(__hip_bfloat16);
  float* nodesum = (float*)p;                                     // N*64 f32 = 25.6 MB
  p += (size_t)N_NODES * 64 * sizeof(float);
  float* cnt = (float*)p;                                         // N f32
  p += (size_t)N_NODES * sizeof(float);
  float* stats = (float*)p;                                       // 512 f32: sum1/sq1, scsh1, sum2/sq2, scsh2
  p += 512 * sizeof(float);
  __hip_bfloat16* h2 = (__hip_bfloat16*)p;                        // N*64 bf16 = 12.8 MB

  // Zero nodesum + cnt + stats (contiguous)
  size_t zbytes = (size_t)N_NODES * 64 * sizeof(float) + (size_t)N_NODES * sizeof(float) + 512 * sizeof(float);
  (void)hipMemsetAsync(nodesum, 0, zbytes, stream);

  edge_mlp1<<<1024, 256, 0, stream>>>(x, ei, ea, W1a, b1a, h1, stats);
  bn_finalize<<<1, 64, 0, stream>>>(stats, g1, be1, stats + 128, 1.0f / (float)N_EDGES);
  edge_mlp2<<<1024, 256, 0, stream>>>(h1, ei + N_EDGES, W2a, b2a, stats + 128, nodesum, cnt);
  node_mlp1<<<512, 256, 0, stream>>>(x, nodesum, cnt, W1b, b1b, h2, stats + 256);
  bn_finalize<<<1, 64, 0, stream>>>(stats + 256, g2, be2, stats + 384, 1.0f / (float)N_NODES);
  node_mlp2<<<512, 256, 0, stream>>>(h2, W2b, b2b, stats + 384, out);
}

// Round 4
// 668.343 us; speedup vs baseline: 2.0359x; 2.0359x over previous
//
#include <hip/hip_runtime.h>
#include <hip/hip_bf16.h>
#include <cstddef>
#include <cstdint>

#define N_NODES 100000
#define N_EDGES 800000
#define EPS 1e-5f

typedef __attribute__((ext_vector_type(8))) short bf16x8;
typedef __attribute__((ext_vector_type(4))) float f32x4;
typedef __attribute__((ext_vector_type(8))) unsigned short u16x8;

#define MFMA16(a, b, c) __builtin_amdgcn_mfma_f32_16x16x32_bf16(a, b, c, 0, 0, 0)

__device__ __forceinline__ unsigned short f2bf(float f) {
  return __builtin_bit_cast(unsigned short, __float2bfloat16(f));
}
__device__ __forceinline__ float bf2f(unsigned short u) {
  return __bfloat162float(__builtin_bit_cast(__hip_bfloat16, u));
}

// ---------------------------------------------------------------------------
// Prep: transpose weights to bf16 Wt[n][k] so MFMA B-fragments read contiguous k.
// Layout in wt: Wt1a[64][128] | Wt2a[64][64] | Wt1b[64][128] | Wt2b[64][64]
// ---------------------------------------------------------------------------
__global__ void prep_w(const float* __restrict__ W1a, const float* __restrict__ W2a,
                       const float* __restrict__ W1b, const float* __restrict__ W2b,
                       unsigned short* __restrict__ wt) {
  int i = blockIdx.x * 256 + threadIdx.x;
  if (i >= 24576) return;
  if (i < 8192) {
    int n = i >> 7, k = i & 127;
    wt[i] = f2bf(W1a[k * 64 + n]);
  } else if (i < 12288) {
    int j = i - 8192; int n = j >> 6, k = j & 63;
    wt[i] = f2bf(W2a[k * 64 + n]);
  } else if (i < 20480) {
    int j = i - 12288; int n = j >> 7, k = j & 127;
    wt[i] = f2bf(W1b[k * 64 + n]);
  } else {
    int j = i - 20480; int n = j >> 6, k = j & 63;
    wt[i] = f2bf(W2b[k * 64 + n]);
  }
}

// ---------------------------------------------------------------------------
// Count edges per destination node.
// ---------------------------------------------------------------------------
__global__ void count_edges(const int* __restrict__ ei_col, float* __restrict__ cnt) {
  int e = blockIdx.x * 256 + threadIdx.x;
  if (e < N_EDGES) atomicAdd(&cnt[ei_col[e]], 1.f);
}

// ---------------------------------------------------------------------------
// BN finalize: reduce 64 partial slots -> scale/shift per column.
// ---------------------------------------------------------------------------
__global__ void bn_finalize(const float* __restrict__ st, const float* __restrict__ g,
                            const float* __restrict__ be, float* __restrict__ scsh,
                            float inv_count) {
  int j = threadIdx.x;
  float s = 0.f, q = 0.f;
  for (int k = 0; k < 64; k++) { s += st[k * 128 + j]; q += st[k * 128 + 64 + j]; }
  float mu = s * inv_count;
  float var = q * inv_count - mu * mu;
  float sc = g[j] * rsqrtf(var + EPS);
  scsh[j] = sc;
  scsh[64 + j] = be[j] - mu * sc;
}

// ---------------------------------------------------------------------------
// MLP layer 1 (K=128) via MFMA. Block = 128 rows x 64 cols, 4 waves.
// A row = concat(x-part, second-part). Fused BN-stat accumulation.
// A stride 136 bf16 (272B, 16B-aligned, bank-balanced); W stride 136.
// ---------------------------------------------------------------------------
__global__ __launch_bounds__(256)
void edge_mlp1_mfma(const float* __restrict__ x, const int* __restrict__ ei_row,
                    const float* __restrict__ ea, const unsigned short* __restrict__ Wt,
                    const float* __restrict__ b1,
                    unsigned short* __restrict__ h1, float* __restrict__ stats) {
  __shared__ unsigned short Al[128 * 136];
  __shared__ unsigned short Wl[64 * 136];
  __shared__ int rows[128];
  int tid = threadIdx.x;
  int base = blockIdx.x * 128;
  if (tid < 128) rows[tid] = ei_row[base + tid];
  // W tile: 64 n x 128 k = 8192 bf16 = 1024 u16x8 chunks -> 4 iters x 256 thr
#pragma unroll
  for (int i = 0; i < 4; i++) {
    int g = i * 256 + tid;
    int n = g >> 4, k0 = (g & 15) * 8;
    *(u16x8*)&Wl[n * 136 + k0] = *(const u16x8*)&Wt[n * 128 + k0];
  }
  __syncthreads();
#pragma unroll
  for (int i = 0; i < 16; i++) {
    int g = i * 256 + tid;
    int e = g >> 5, part = g & 31;
    float4 v; int k0;
    if (part < 16) { v = *(const float4*)&x[(size_t)rows[e] * 64 + part * 4]; k0 = part * 4; }
    else { v = *(const float4*)&ea[(size_t)(base + e) * 64 + (part - 16) * 4]; k0 = 64 + (part - 16) * 4; }
    ushort4 b4;
    b4.x = f2bf(v.x); b4.y = f2bf(v.y); b4.z = f2bf(v.z); b4.w = f2bf(v.w);
    *(ushort4*)&Al[e * 136 + k0] = b4;
  }
  __syncthreads();

  int l = tid & 63, w = tid >> 6;
  int m16 = l & 15, g4 = l >> 4;
  f32x4 acc[2][4];
#pragma unroll
  for (int nt = 0; nt < 4; nt++) {
    float bv = b1[nt * 16 + m16];
#pragma unroll
    for (int mt = 0; mt < 2; mt++) acc[mt][nt] = (f32x4){bv, bv, bv, bv};
  }
#pragma unroll
  for (int kit = 0; kit < 4; kit++) {
    bf16x8 a[2], b[4];
#pragma unroll
    for (int mt = 0; mt < 2; mt++)
      a[mt] = *(const bf16x8*)&Al[(w * 32 + mt * 16 + m16) * 136 + kit * 32 + g4 * 8];
#pragma unroll
    for (int nt = 0; nt < 4; nt++)
      b[nt] = *(const bf16x8*)&Wl[(nt * 16 + m16) * 136 + kit * 32 + g4 * 8];
#pragma unroll
    for (int mt = 0; mt < 2; mt++)
#pragma unroll
      for (int nt = 0; nt < 4; nt++)
        acc[mt][nt] = MFMA16(a[mt], b[nt], acc[mt][nt]);
  }

  float ps[4] = {0, 0, 0, 0}, pq[4] = {0, 0, 0, 0};
#pragma unroll
  for (int mt = 0; mt < 2; mt++) {
    int erow = base + w * 32 + mt * 16 + g4 * 4;
#pragma unroll
    for (int nt = 0; nt < 4; nt++) {
      int ch = nt * 16 + m16;
#pragma unroll
      for (int r = 0; r < 4; r++) {
        float v = acc[mt][nt][r];
        h1[(size_t)(erow + r) * 64 + ch] = f2bf(v);
        ps[nt] += v; pq[nt] += v * v;
      }
    }
  }
#pragma unroll
  for (int nt = 0; nt < 4; nt++) {
    ps[nt] += __shfl_xor(ps[nt], 16); ps[nt] += __shfl_xor(ps[nt], 32);
    pq[nt] += __shfl_xor(pq[nt], 16); pq[nt] += __shfl_xor(pq[nt], 32);
  }
  float ssel = (g4 == 0) ? ps[0] : (g4 == 1) ? ps[1] : (g4 == 2) ? ps[2] : ps[3];
  float qsel = (g4 == 0) ? pq[0] : (g4 == 1) ? pq[1] : (g4 == 2) ? pq[2] : pq[3];
  int slot = blockIdx.x & 63;
  atomicAdd(&stats[slot * 128 + l], ssel);
  atomicAdd(&stats[slot * 128 + 64 + l], qsel);
}

// ---------------------------------------------------------------------------
// Node MLP layer 1 (K=128): A = concat(x[n], nodesum[n]*inv). Partial-block guards.
// ---------------------------------------------------------------------------
__global__ __launch_bounds__(256)
void node_mlp1_mfma(const float* __restrict__ x, const float* __restrict__ ns,
                    const float* __restrict__ cnt, const unsigned short* __restrict__ Wt,
                    const float* __restrict__ b1,
                    unsigned short* __restrict__ h2, float* __restrict__ stats) {
  __shared__ unsigned short Al[128 * 136];
  __shared__ unsigned short Wl[64 * 136];
  __shared__ float invl[128];
  int tid = threadIdx.x;
  int base = blockIdx.x * 128;
  if (tid < 128) {
    int r = base + tid;
    float c = (r < N_NODES) ? cnt[r] : 1.f;
    invl[tid] = 1.f / fmaxf(c, 1.f);
  }
  // W tile: 8192 bf16 -> 4 iters
#pragma unroll
  for (int i = 0; i < 4; i++) {
    int g = i * 256 + tid;
    int n = g >> 4, k0 = (g & 15) * 8;
    *(u16x8*)&Wl[n * 136 + k0] = *(const u16x8*)&Wt[n * 128 + k0];
  }
  __syncthreads();
#pragma unroll
  for (int i = 0; i < 16; i++) {
    int g = i * 256 + tid;
    int e = g >> 5, part = g & 31;
    int r = base + e;
    float4 v = make_float4(0.f, 0.f, 0.f, 0.f);
    int k0 = (part < 16) ? part * 4 : 64 + (part - 16) * 4;
    if (r < N_NODES) {
      if (part < 16) v = *(const float4*)&x[(size_t)r * 64 + part * 4];
      else {
        v = *(const float4*)&ns[(size_t)r * 64 + (part - 16) * 4];
        float iv = invl[e];
        v.x *= iv; v.y *= iv; v.z *= iv; v.w *= iv;
      }
    }
    ushort4 b4;
    b4.x = f2bf(v.x); b4.y = f2bf(v.y); b4.z = f2bf(v.z); b4.w = f2bf(v.w);
    *(ushort4*)&Al[e * 136 + k0] = b4;
  }
  __syncthreads();

  int l = tid & 63, w = tid >> 6;
  int m16 = l & 15, g4 = l >> 4;
  f32x4 acc[2][4];
#pragma unroll
  for (int nt = 0; nt < 4; nt++) {
    float bv = b1[nt * 16 + m16];
#pragma unroll
    for (int mt = 0; mt < 2; mt++) acc[mt][nt] = (f32x4){bv, bv, bv, bv};
  }
#pragma unroll
  for (int kit = 0; kit < 4; kit++) {
    bf16x8 a[2], b[4];
#pragma unroll
    for (int mt = 0; mt < 2; mt++)
      a[mt] = *(const bf16x8*)&Al[(w * 32 + mt * 16 + m16) * 136 + kit * 32 + g4 * 8];
#pragma unroll
    for (int nt = 0; nt < 4; nt++)
      b[nt] = *(const bf16x8*)&Wl[(nt * 16 + m16) * 136 + kit * 32 + g4 * 8];
#pragma unroll
    for (int mt = 0; mt < 2; mt++)
#pragma unroll
      for (int nt = 0; nt < 4; nt++)
        acc[mt][nt] = MFMA16(a[mt], b[nt], acc[mt][nt]);
  }

  float ps[4] = {0, 0, 0, 0}, pq[4] = {0, 0, 0, 0};
#pragma unroll
  for (int mt = 0; mt < 2; mt++) {
    int nrow = base + w * 32 + mt * 16 + g4 * 4;
#pragma unroll
    for (int nt = 0; nt < 4; nt++) {
      int ch = nt * 16 + m16;
#pragma unroll
      for (int r = 0; r < 4; r++) {
        float v = acc[mt][nt][r];
        if (nrow + r < N_NODES) {
          h2[(size_t)(nrow + r) * 64 + ch] = f2bf(v);
          ps[nt] += v; pq[nt] += v * v;
        }
      }
    }
  }
#pragma unroll
  for (int nt = 0; nt < 4; nt++) {
    ps[nt] += __shfl_xor(ps[nt], 16); ps[nt] += __shfl_xor(ps[nt], 32);
    pq[nt] += __shfl_xor(pq[nt], 16); pq[nt] += __shfl_xor(pq[nt], 32);
  }
  float ssel = (g4 == 0) ? ps[0] : (g4 == 1) ? ps[1] : (g4 == 2) ? ps[2] : ps[3];
  float qsel = (g4 == 0) ? pq[0] : (g4 == 1) ? pq[1] : (g4 == 2) ? pq[2] : pq[3];
  int slot = blockIdx.x & 63;
  atomicAdd(&stats[slot * 128 + l], ssel);
  atomicAdd(&stats[slot * 128 + 64 + l], qsel);
}

// ---------------------------------------------------------------------------
// Edge MLP layer 2 (K=64): BN+ReLU fused into staging; scatter-add epilogue.
// ---------------------------------------------------------------------------
__global__ __launch_bounds__(256)
void edge_mlp2_mfma(const unsigned short* __restrict__ h1, const int* __restrict__ ei_col,
                    const unsigned short* __restrict__ Wt2, const float* __restrict__ b2,
                    const float* __restrict__ scsh, float* __restrict__ nodesum) {
  __shared__ unsigned short Al[128 * 72];
  __shared__ unsigned short Wl[64 * 72];
  __shared__ int cols[128];
  int tid = threadIdx.x;
  int base = blockIdx.x * 128;
  if (tid < 128) cols[tid] = ei_col[base + tid];
  // W tile: 64 x 64 = 4096 bf16 = 512 chunks -> 2 iters
#pragma unroll
  for (int i = 0; i < 2; i++) {
    int g = i * 256 + tid;
    int n = g >> 3, k0 = (g & 7) * 8;
    *(u16x8*)&Wl[n * 72 + k0] = *(const u16x8*)&Wt2[n * 64 + k0];
  }
  int kp = tid & 7, k0s = kp * 8;
  float sc[8], sh[8];
#pragma unroll
  for (int j = 0; j < 8; j++) { sc[j] = scsh[k0s + j]; sh[j] = scsh[64 + k0s + j]; }
#pragma unroll
  for (int i = 0; i < 4; i++) {
    int e = i * 32 + (tid >> 3);
    u16x8 hv = *(const u16x8*)&h1[(size_t)(base + e) * 64 + k0s];
    u16x8 o;
#pragma unroll
    for (int j = 0; j < 8; j++) {
      float v = fmaxf(fmaf(bf2f(hv[j]), sc[j], sh[j]), 0.f);
      o[j] = f2bf(v);
    }
    *(u16x8*)&Al[e * 72 + k0s] = o;
  }
  __syncthreads();

  int l = tid & 63, w = tid >> 6;
  int m16 = l & 15, g4 = l >> 4;
  f32x4 acc[2][4];
#pragma unroll
  for (int nt = 0; nt < 4; nt++) {
    float bv = b2[nt * 16 + m16];
#pragma unroll
    for (int mt = 0; mt < 2; mt++) acc[mt][nt] = (f32x4){bv, bv, bv, bv};
  }
#pragma unroll
  for (int kit = 0; kit < 2; kit++) {
    bf16x8 a[2], b[4];
#pragma unroll
    for (int mt = 0; mt < 2; mt++)
      a[mt] = *(const bf16x8*)&Al[(w * 32 + mt * 16 + m16) * 72 + kit * 32 + g4 * 8];
#pragma unroll
    for (int nt = 0; nt < 4; nt++)
      b[nt] = *(const bf16x8*)&Wl[(nt * 16 + m16) * 72 + kit * 32 + g4 * 8];
#pragma unroll
    for (int mt = 0; mt < 2; mt++)
#pragma unroll
      for (int nt = 0; nt < 4; nt++)
        acc[mt][nt] = MFMA16(a[mt], b[nt], acc[mt][nt]);
  }
#pragma unroll
  for (int mt = 0; mt < 2; mt++) {
#pragma unroll
    for (int r = 0; r < 4; r++) {
      int el = w * 32 + mt * 16 + g4 * 4 + r;
      int node = cols[el];
#pragma unroll
      for (int nt = 0; nt < 4; nt++) {
        int ch = nt * 16 + m16;
        atomicAdd(&nodesum[(size_t)node * 64 + ch], acc[mt][nt][r]);
      }
    }
  }
}

// ---------------------------------------------------------------------------
// Node MLP layer 2 (K=64): BN+ReLU fused into staging; direct store. Guards.
// ---------------------------------------------------------------------------
__global__ __launch_bounds__(256)
void node_mlp2_mfma(const unsigned short* __restrict__ h2, const unsigned short* __restrict__ Wt2,
                    const float* __restrict__ b2, const float* __restrict__ scsh,
                    float* __restrict__ out) {
  __shared__ unsigned short Al[128 * 72];
  __shared__ unsigned short Wl[64 * 72];
  int tid = threadIdx.x;
  int base = blockIdx.x * 128;
#pragma unroll
  for (int i = 0; i < 2; i++) {
    int g = i * 256 + tid;
    int n = g >> 3, k0 = (g & 7) * 8;
    *(u16x8*)&Wl[n * 72 + k0] = *(const u16x8*)&Wt2[n * 64 + k0];
  }
  int kp = tid & 7, k0s = kp * 8;
  float sc[8], sh[8];
#pragma unroll
  for (int j = 0; j < 8; j++) { sc[j] = scsh[k0s + j]; sh[j] = scsh[64 + k0s + j]; }
#pragma unroll
  for (int i = 0; i < 4; i++) {
    int e = i * 32 + (tid >> 3);
    int r = base + e;
    u16x8 o;
    if (r < N_NODES) {
      u16x8 hv = *(const u16x8*)&h2[(size_t)r * 64 + k0s];
#pragma unroll
      for (int j = 0; j < 8; j++) {
        float v = fmaxf(fmaf(bf2f(hv[j]), sc[j], sh[j]), 0.f);
        o[j] = f2bf(v);
      }
    } else {
#pragma unroll
      for (int j = 0; j < 8; j++) o[j] = 0;
    }
    *(u16x8*)&Al[e * 72 + k0s] = o;
  }
  __syncthreads();

  int l = tid & 63, w = tid >> 6;
  int m16 = l & 15, g4 = l >> 4;
  f32x4 acc[2][4];
#pragma unroll
  for (int nt = 0; nt < 4; nt++) {
    float bv = b2[nt * 16 + m16];
#pragma unroll
    for (int mt = 0; mt < 2; mt++) acc[mt][nt] = (f32x4){bv, bv, bv, bv};
  }
#pragma unroll
  for (int kit = 0; kit < 2; kit++) {
    bf16x8 a[2], b[4];
#pragma unroll
    for (int mt = 0; mt < 2; mt++)
      a[mt] = *(const bf16x8*)&Al[(w * 32 + mt * 16 + m16) * 72 + kit * 32 + g4 * 8];
#pragma unroll
    for (int nt = 0; nt < 4; nt++)
      b[nt] = *(const bf16x8*)&Wl[(nt * 16 + m16) * 72 + kit * 32 + g4 * 8];
#pragma unroll
    for (int mt = 0; mt < 2; mt++)
#pragma unroll
      for (int nt = 0; nt < 4; nt++)
        acc[mt][nt] = MFMA16(a[mt], b[nt], acc[mt][nt]);
  }
#pragma unroll
  for (int mt = 0; mt < 2; mt++) {
    int nrow = base + w * 32 + mt * 16 + g4 * 4;
#pragma unroll
    for (int nt = 0; nt < 4; nt++) {
      int ch = nt * 16 + m16;
#pragma unroll
      for (int r = 0; r < 4; r++) {
        if (nrow + r < N_NODES) out[(size_t)(nrow + r) * 64 + ch] = acc[mt][nt][r];
      }
    }
  }
}

// ---------------------------------------------------------------------------
extern "C" void kernel_launch(void* const* d_in, const int* in_sizes, int n_in,
                              void* d_out, int out_size, void* d_ws, size_t ws_size,
                              hipStream_t stream) {
  const float* x   = (const float*)d_in[0];
  const int*   ei  = (const int*)d_in[1];   // [2,E]: rows then cols
  const float* ea  = (const float*)d_in[2];
  const float* W1a = (const float*)d_in[5];
  const float* b1a = (const float*)d_in[6];
  const float* g1  = (const float*)d_in[7];
  const float* be1 = (const float*)d_in[8];
  const float* W2a = (const float*)d_in[9];
  const float* b2a = (const float*)d_in[10];
  const float* W1b = (const float*)d_in[11];
  const float* b1b = (const float*)d_in[12];
  const float* g2  = (const float*)d_in[13];
  const float* be2 = (const float*)d_in[14];
  const float* W2b = (const float*)d_in[15];
  const float* b2b = (const float*)d_in[16];
  float* out = (float*)d_out;

  // Workspace layout
  char* p = (char*)d_ws;
  unsigned short* h1 = (unsigned short*)p;      p += (size_t)N_EDGES * 64 * 2;  // 102.4 MB
  float* nodesum = (float*)p;                   p += (size_t)N_NODES * 64 * 4;  // 25.6 MB
  float* cnt = (float*)p;                       p += (size_t)N_NODES * 4;       // 0.4 MB
  float* stats1 = (float*)p;                    p += 8192 * 4;                  // 64 slots x 128
  float* stats2 = (float*)p;                    p += 8192 * 4;
  float* scsh1 = (float*)p;                     p += 128 * 4;
  float* scsh2 = (float*)p;                     p += 128 * 4;
  unsigned short* h2 = (unsigned short*)p;      p += (size_t)N_NODES * 64 * 2;  // 12.8 MB
  unsigned short* wt = (unsigned short*)p;      // 24576 bf16
  unsigned short* wt1a = wt;
  unsigned short* wt2a = wt + 8192;
  unsigned short* wt1b = wt + 12288;
  unsigned short* wt2b = wt + 20480;

  // Zero nodesum + cnt + stats (contiguous)
  size_t zbytes = (size_t)N_NODES * 64 * 4 + (size_t)N_NODES * 4 + 2 * 8192 * 4;
  (void)hipMemsetAsync(nodesum, 0, zbytes, stream);

  prep_w<<<96, 256, 0, stream>>>(W1a, W2a, W1b, W2b, wt);
  edge_mlp1_mfma<<<6250, 256, 0, stream>>>(x, ei, ea, wt1a, b1a, h1, stats1);
  bn_finalize<<<1, 64, 0, stream>>>(stats1, g1, be1, scsh1, 1.0f / (float)N_EDGES);
  count_edges<<<3125, 256, 0, stream>>>(ei + N_EDGES, cnt);
  edge_mlp2_mfma<<<6250, 256, 0, stream>>>(h1, ei + N_EDGES, wt2a, b2a, scsh1, nodesum);
  node_mlp1_mfma<<<782, 256, 0, stream>>>(x, nodesum, cnt, wt1b, b1b, h2, stats2);
  bn_finalize<<<1, 64, 0, stream>>>(stats2, g2, be2, scsh2, 1.0f / (float)N_NODES);
  node_mlp2_mfma<<<782, 256, 0, stream>>>(h2, wt2b, b2b, scsh2, out);
}